// Round 2
// baseline (472.276 us; speedup 1.0000x reference)
//
#include <hip/hip_runtime.h>

typedef __bf16 bf16;
typedef bf16 bf16x8 __attribute__((ext_vector_type(8)));
typedef bf16 bf16x4 __attribute__((ext_vector_type(4)));
typedef float f32x4 __attribute__((ext_vector_type(4)));

#define MFMA16(a, b, c) __builtin_amdgcn_mfma_f32_16x16x32_bf16((a), (b), (c), 0, 0, 0)

__device__ __forceinline__ void gload_lds16(const bf16* g, bf16* l) {
  __builtin_amdgcn_global_load_lds(
      (const __attribute__((address_space(1))) void*)g,
      (__attribute__((address_space(3))) void*)l, 16, 0, 0);
}

// ---------------------------------------------------------------------------
// fp32 -> bf16 convert, float4 in / 4x bf16 out
// ---------------------------------------------------------------------------
__global__ __launch_bounds__(256) void cvt_f32_bf16(const float* __restrict__ src,
                                                    bf16* __restrict__ dst, int n4) {
  int i = blockIdx.x * blockDim.x + threadIdx.x;
  if (i < n4) {
    float4 v = ((const float4*)src)[i];
    bf16x4 o;
    o[0] = (bf16)v.x; o[1] = (bf16)v.y; o[2] = (bf16)v.z; o[3] = (bf16)v.w;
    ((bf16x4*)dst)[i] = o;
  }
}

// ---------------------------------------------------------------------------
// GEMM C = A * B^T  (A: M x K row-major bf16, B: N x K row-major bf16)
// Output type templated: bf16 for intermediates, float for final d_out.
// 128x128 block tile, BK=64, 4 waves (2x2), each wave 64x64 = 4x4 MFMA frags.
// LDS staged via global_load_lds(16B) with XOR swizzle (c8 ^= row&7) so the
// ds_read_b128 fragment reads are 2-way-max bank conflicts (free per m136).
// ---------------------------------------------------------------------------
template <typename OutT>
__global__ __launch_bounds__(256) void gemm_bt(const bf16* __restrict__ A,
                                               const bf16* __restrict__ B,
                                               OutT* __restrict__ C,
                                               int M, int N, int K) {
  __shared__ __align__(16) bf16 As[128 * 64];
  __shared__ __align__(16) bf16 Bs[128 * 64];
  const int tid = threadIdx.x;
  const int w = tid >> 6, lane = tid & 63;
  const int l15 = lane & 15, quad = lane >> 4;
  const int m0 = blockIdx.y * 128, n0 = blockIdx.x * 128;
  const int wm = (w >> 1) * 64, wn = (w & 1) * 64;

  f32x4 acc[4][4] = {};

  for (int k0 = 0; k0 < K; k0 += 64) {
    // stage A tile (128 rows x 64 cols = 1024 granules of 8 bf16)
#pragma unroll
    for (int i = 0; i < 4; i++) {
      int s = w * 256 + i * 64 + lane;
      int row = s >> 3;
      int c8 = (s & 7) ^ (row & 7);
      gload_lds16(A + (size_t)(m0 + row) * K + k0 + c8 * 8, As + (w * 256 + i * 64) * 8);
    }
#pragma unroll
    for (int i = 0; i < 4; i++) {
      int s = w * 256 + i * 64 + lane;
      int row = s >> 3;
      int c8 = (s & 7) ^ (row & 7);
      gload_lds16(B + (size_t)(n0 + row) * K + k0 + c8 * 8, Bs + (w * 256 + i * 64) * 8);
    }
    __syncthreads();

#pragma unroll
    for (int kk = 0; kk < 2; kk++) {
      bf16x8 af[4], bfr[4];
#pragma unroll
      for (int mt = 0; mt < 4; mt++) {
        int row = wm + mt * 16 + l15;
        int slot = row * 8 + ((kk * 4 + quad) ^ (row & 7));
        af[mt] = *(const bf16x8*)(As + slot * 8);
      }
#pragma unroll
      for (int nt = 0; nt < 4; nt++) {
        int row = wn + nt * 16 + l15;
        int slot = row * 8 + ((kk * 4 + quad) ^ (row & 7));
        bfr[nt] = *(const bf16x8*)(Bs + slot * 8);
      }
#pragma unroll
      for (int mt = 0; mt < 4; mt++)
#pragma unroll
        for (int nt = 0; nt < 4; nt++)
          acc[mt][nt] = MFMA16(af[mt], bfr[nt], acc[mt][nt]);
    }
    __syncthreads();
  }

  // epilogue: C/D layout col = lane&15, row = quad*4 + r  [m89/m91 verified]
#pragma unroll
  for (int mt = 0; mt < 4; mt++)
#pragma unroll
    for (int nt = 0; nt < 4; nt++) {
      int row = m0 + wm + mt * 16 + quad * 4;
      int col = n0 + wn + nt * 16 + l15;
#pragma unroll
      for (int r = 0; r < 4; r++)
        C[(size_t)(row + r) * N + col] = (OutT)acc[mt][nt][r];
    }
}

// ---------------------------------------------------------------------------
// Per-(s, head) RMSNorm + RoPE. One wave per (s,h); h<16 -> Q head, else K.
// Lane l holds x[l] and x[l+64]; cos/sin duplicate halves so c,s index = l.
// Q is pre-scaled by 1/sqrt(D) so attention skips the score scaling.
// ---------------------------------------------------------------------------
__global__ __launch_bounds__(256) void normrope(const bf16* __restrict__ QKVb,
                                                const float* __restrict__ cosb,
                                                const float* __restrict__ sinb,
                                                const float* __restrict__ qw,
                                                const float* __restrict__ kw,
                                                bf16* __restrict__ Qb,
                                                bf16* __restrict__ Kb) {
  const int wid = (blockIdx.x * blockDim.x + threadIdx.x) >> 6;
  const int lane = threadIdx.x & 63;
  const int s = wid / 24;
  const int h = wid % 24;
  const bool isq = (h < 16);
  const int col0 = isq ? h * 128 : 2048 + (h - 16) * 128;
  const float* wt = isq ? qw : kw;

  const bf16* row = QKVb + (size_t)s * 4096 + col0;
  float x1 = (float)row[lane];
  float x2 = (float)row[lane + 64];

  float ss = x1 * x1 + x2 * x2;
#pragma unroll
  for (int m = 32; m >= 1; m >>= 1) ss += __shfl_xor(ss, m, 64);
  float rs = rsqrtf(ss * (1.0f / 128.0f) + 1e-6f);

  float c = cosb[(size_t)s * 128 + lane];
  float sn = sinb[(size_t)s * 128 + lane];
  float xn1 = x1 * rs * wt[lane];
  float xn2 = x2 * rs * wt[lane + 64];
  float o1 = xn1 * c - xn2 * sn;
  float o2 = xn2 * c + xn1 * sn;
  const float scale = isq ? 0.08838834764831845f : 1.0f;  // D^-0.5 folded into Q
  o1 *= scale; o2 *= scale;

  bf16* dst = isq ? (Qb + ((size_t)h * 4096 + s) * 128)
                  : (Kb + ((size_t)(h - 16) * 4096 + s) * 128);
  dst[lane] = (bf16)o1;
  dst[lane + 64] = (bf16)o2;
}

// ---------------------------------------------------------------------------
// Sliding-window GQA flash attention.
// Block = (head h, 64 queries). 4 waves, wave w owns queries q0..q0+15.
// K tiles of 32 keys. Per tile: QK^T (8 MFMAs), online softmax, P->LDS
// (C-layout -> A-layout transform), PV (8 MFMAs) with V staged transposed.
// V read straight from QKVb (no norm/rope on V).
// ---------------------------------------------------------------------------
__global__ __launch_bounds__(256) void attn_kernel(const bf16* __restrict__ Qb,
                                                   const bf16* __restrict__ Kb,
                                                   const bf16* __restrict__ QKVb,
                                                   bf16* __restrict__ Ob) {
  const int SEQ = 4096, W = 1024;
  __shared__ __align__(16) bf16 Ks[32 * 136];   // [key][d] pad->2-way conflicts
  __shared__ __align__(16) bf16 Vs[128 * 40];   // [d][key] transposed, pad 40
  __shared__ __align__(16) bf16 Ps[4][16 * 40]; // per-wave P, [q][key] pad 40

  const int h = blockIdx.y, kvh = h >> 1;
  const int qb0 = blockIdx.x * 64;
  const int tid = threadIdx.x, w = tid >> 6, lane = tid & 63;
  const int l15 = lane & 15, quad = lane >> 4;
  const int q0 = qb0 + w * 16;

  // Q fragments in registers: A[m=l15][k=quad*8+j], 4 k-blocks of 32
  bf16x8 qf[4];
  {
    const bf16* qp = Qb + ((size_t)h * SEQ + q0 + l15) * 128 + quad * 8;
#pragma unroll
    for (int kb = 0; kb < 4; kb++) qf[kb] = *(const bf16x8*)(qp + kb * 32);
  }

  f32x4 o[8] = {};
  float mrun[4] = {-1e30f, -1e30f, -1e30f, -1e30f};
  float lrun[4] = {};

  int kstart = qb0 - (W - 1); if (kstart < 0) kstart = 0;
  const int kt0 = kstart >> 5;
  const int kt1 = (qb0 + 63) >> 5;

  for (int kt = kt0; kt <= kt1; ++kt) {
    const int k0 = kt * 32;
    // stage K tile: 32 keys x 128 d
    for (int g = tid; g < 512; g += 256) {
      int row = g >> 4, c8 = g & 15;
      *(bf16x8*)(Ks + row * 136 + c8 * 8) =
          *(const bf16x8*)(Kb + ((size_t)kvh * SEQ + k0 + row) * 128 + c8 * 8);
    }
    // stage V tile transposed: read [key][d] from QKVb, write [d][key]
    for (int g = tid; g < 512; g += 256) {
      int k = g & 31, c8 = g >> 5;
      bf16x8 v = *(const bf16x8*)(QKVb + (size_t)(k0 + k) * 4096 + 3072 + kvh * 128 + c8 * 8);
#pragma unroll
      for (int j = 0; j < 8; j++) Vs[(c8 * 8 + j) * 40 + k] = v[j];
    }
    __syncthreads();

    const bool active = (k0 + 31 >= q0 - (W - 1)) && (k0 <= q0 + 15);
    if (active) {
      f32x4 sf0 = {}, sf1 = {};
#pragma unroll
      for (int kb = 0; kb < 4; kb++) {
        bf16x8 b0 = *(const bf16x8*)(Ks + l15 * 136 + kb * 32 + quad * 8);
        bf16x8 b1 = *(const bf16x8*)(Ks + (16 + l15) * 136 + kb * 32 + quad * 8);
        sf0 = MFMA16(qf[kb], b0, sf0);
        sf1 = MFMA16(qf[kb], b1, sf1);
      }
      // scores: row i = q0+quad*4+r, col j = k0+sub*16+l15 (scale already in Q)
      float sv0[4], sv1[4], tmax[4];
      bool ok0[4], ok1[4];
#pragma unroll
      for (int r = 0; r < 4; r++) {
        int i = q0 + quad * 4 + r;
        int j0 = k0 + l15, j1 = k0 + 16 + l15;
        ok0[r] = (j0 <= i) && (j0 > i - W);
        ok1[r] = (j1 <= i) && (j1 > i - W);
        sv0[r] = ok0[r] ? sf0[r] : -1e30f;
        sv1[r] = ok1[r] ? sf1[r] : -1e30f;
        tmax[r] = fmaxf(sv0[r], sv1[r]);
      }
#pragma unroll
      for (int m = 8; m >= 1; m >>= 1)
#pragma unroll
        for (int r = 0; r < 4; r++) tmax[r] = fmaxf(tmax[r], __shfl_xor(tmax[r], m, 64));

      float alpha[4], p0[4], p1[4], rsum[4];
#pragma unroll
      for (int r = 0; r < 4; r++) {
        float mn = fmaxf(mrun[r], tmax[r]);
        alpha[r] = __expf(mrun[r] - mn);  // exp(0)=1 if both -1e30; exp(-inf)=0 ok
        mrun[r] = mn;
        p0[r] = ok0[r] ? __expf(sv0[r] - mn) : 0.0f;  // mask forces P=0: no NaNs
        p1[r] = ok1[r] ? __expf(sv1[r] - mn) : 0.0f;
        rsum[r] = p0[r] + p1[r];
      }
#pragma unroll
      for (int m = 8; m >= 1; m >>= 1)
#pragma unroll
        for (int r = 0; r < 4; r++) rsum[r] += __shfl_xor(rsum[r], m, 64);
#pragma unroll
      for (int r = 0; r < 4; r++) lrun[r] = lrun[r] * alpha[r] + rsum[r];
#pragma unroll
      for (int n16 = 0; n16 < 8; n16++)
#pragma unroll
        for (int r = 0; r < 4; r++) o[n16][r] *= alpha[r];

      // P: C-layout -> LDS -> A-layout (per-wave region, in-order LDS per wave)
      bf16* pb = &Ps[w][0];
#pragma unroll
      for (int r = 0; r < 4; r++) {
        pb[(quad * 4 + r) * 40 + l15] = (bf16)p0[r];
        pb[(quad * 4 + r) * 40 + 16 + l15] = (bf16)p1[r];
      }
      asm volatile("s_waitcnt lgkmcnt(0)" ::: "memory");
      bf16x8 pf = *(const bf16x8*)(pb + l15 * 40 + quad * 8);
#pragma unroll
      for (int n16 = 0; n16 < 8; n16++) {
        bf16x8 vf = *(const bf16x8*)(Vs + (n16 * 16 + l15) * 40 + quad * 8);
        o[n16] = MFMA16(pf, vf, o[n16]);
      }
    }
    __syncthreads();
  }

  float inv[4];
#pragma unroll
  for (int r = 0; r < 4; r++) inv[r] = 1.0f / lrun[r];  // every row has >=1 key
#pragma unroll
  for (int n16 = 0; n16 < 8; n16++)
#pragma unroll
    for (int r = 0; r < 4; r++) {
      int i = q0 + quad * 4 + r;
      Ob[(size_t)i * 2048 + h * 128 + n16 * 16 + l15] = (bf16)(o[n16][r] * inv[r]);
    }
}

// ---------------------------------------------------------------------------
// Orchestration
// ---------------------------------------------------------------------------
extern "C" void kernel_launch(void* const* d_in, const int* in_sizes, int n_in,
                              void* d_out, int out_size, void* d_ws, size_t ws_size,
                              hipStream_t stream) {
  const float* hid  = (const float*)d_in[0];
  const float* cosb = (const float*)d_in[1];
  const float* sinb = (const float*)d_in[2];
  const float* Wq   = (const float*)d_in[3];
  const float* Wk   = (const float*)d_in[4];
  const float* Wv   = (const float*)d_in[5];
  const float* Wo   = (const float*)d_in[6];
  const float* qw   = (const float*)d_in[7];
  const float* kw   = (const float*)d_in[8];

  if (ws_size < (size_t)(112u) * 1024u * 1024u) return;  // need 112 MB scratch

  char* ws = (char*)d_ws;
  bf16* Xbf  = (bf16*)(ws);                         // 4096x2048      (16 MB)
  bf16* Wcat = (bf16*)(ws + (16u << 20));           // [Wq;Wk;Wv] 4096x2048
  bf16* Wob  = (bf16*)(ws + (32u << 20));           // 2048x2048      (8 MB)
  bf16* QKVb = (bf16*)(ws + (40u << 20));           // 4096x4096      (32 MB)
  bf16* Qb   = (bf16*)(ws + (72u << 20));           // [16][4096][128](16 MB)
  bf16* Kb   = (bf16*)(ws + (88u << 20));           // [8][4096][128] (8 MB)
  bf16* Ob   = (bf16*)(ws + (96u << 20));           // 4096x2048      (16 MB)

  cvt_f32_bf16<<<8192, 256, 0, stream>>>(hid, Xbf, 2097152);
  cvt_f32_bf16<<<4096, 256, 0, stream>>>(Wq, Wcat, 1048576);
  cvt_f32_bf16<<<2048, 256, 0, stream>>>(Wk, Wcat + 4194304, 524288);
  cvt_f32_bf16<<<2048, 256, 0, stream>>>(Wv, Wcat + 6291456, 524288);
  cvt_f32_bf16<<<4096, 256, 0, stream>>>(Wo, Wob, 1048576);

  gemm_bt<bf16><<<dim3(32, 32), 256, 0, stream>>>(Xbf, Wcat, QKVb, 4096, 4096, 2048);
  normrope<<<24576, 256, 0, stream>>>(QKVb, cosb, sinb, qw, kw, Qb, Kb);
  attn_kernel<<<dim3(64, 16), 256, 0, stream>>>(Qb, Kb, QKVb, Ob);
  gemm_bt<float><<<dim3(16, 32), 256, 0, stream>>>(Ob, Wob, (float*)d_out, 4096, 2048, 2048);
}